// Round 16
// baseline (547.901 us; speedup 1.0000x reference)
//
#include <hip/hip_runtime.h>
#include <hip/hip_bf16.h>

// R-GCN 2-layer forward, round-18: round-17 (506us) + NONTEMPORAL ACC STORE
// (store side ONLY). aggregate FETCH=190.9MB vs ~35MB compulsory: the 200MB
// ACC write stream allocates through L3 and evicts the 25.6MB hb gather table.
// Unlike round-11b (which also nt'd gemm's A-loads while chunked ACC was
// partially L3-resident), ACC is now 204.8MB — gemm reads it from HBM anyway,
// so keeping it out of L3 costs gemm ~nothing and saves aggregate ~150MB of
// HBM re-fetch per dispatch. All else byte-identical to round-17.

#define D 128
#define KTOT 1152
#define KACC 1024
#define BK 32
#define BSH 9            // log2(coarse bucket size in nodes)
#define BSZ 512          // nodes per coarse bucket
#define TILE 4096        // edges per scatterA WG

typedef __attribute__((ext_vector_type(8))) __bf16 bf16x8;
typedef __attribute__((ext_vector_type(8))) unsigned short us8;
typedef __attribute__((ext_vector_type(4))) unsigned short us4;
typedef __attribute__((ext_vector_type(4))) float f32x4;
typedef __attribute__((ext_vector_type(4))) unsigned int ui4;

__device__ __forceinline__ unsigned short f2bf(float f) {
    union { float f; unsigned u; } v; v.f = f;
    unsigned r = v.u + 0x7FFF + ((v.u >> 16) & 1);   // RNE
    return (unsigned short)(r >> 16);
}
__device__ __forceinline__ float bf2f(unsigned short u) {
    return __uint_as_float((unsigned)u << 16);
}

__device__ __forceinline__ void ntstore16(unsigned short* p, us8 v) {
    union { us8 v; ui4 u; } cv; cv.v = v;
    __builtin_nontemporal_store(cv.u, (ui4*)p);
}

__device__ __forceinline__ int lds_off(int row, int c) {
    return row * 32 + ((c ^ ((row >> 1) & 3)) << 3);
}

// ---------------- sort pass A: coarse-bucket histogram / scan / tile-sorted scatter ----------------

__global__ __launch_bounds__(256) void histA_kernel(const int* __restrict__ dst,
                                                    int* __restrict__ bcnt, int E, int nbuck) {
    __shared__ int c[1024];
    int t = threadIdx.x;
    for (int i = t; i < nbuck; i += 256) c[i] = 0;
    __syncthreads();
    int stride = gridDim.x * 256;
    for (int e = blockIdx.x * 256 + t; e < E; e += stride)
        atomicAdd(&c[dst[e] >> BSH], 1);
    __syncthreads();
    for (int i = t; i < nbuck; i += 256)
        if (c[i]) atomicAdd(&bcnt[i], c[i]);
}

__global__ __launch_bounds__(1024) void scanA_kernel(const int* __restrict__ bcnt,
                                                     int* __restrict__ boffs,
                                                     int* __restrict__ bhead, int nbuck) {
    int t = threadIdx.x;
    int v = (t < nbuck) ? bcnt[t] : 0;
    int lane = t & 63, w = t >> 6;
    int inc = v;
    #pragma unroll
    for (int off = 1; off < 64; off <<= 1) {
        int n = __shfl_up(inc, off, 64);
        if (lane >= off) inc += n;
    }
    __shared__ int ws[16];
    if (lane == 63) ws[w] = inc;
    __syncthreads();
    int wbase = 0;
    for (int i = 0; i < w; ++i) wbase += ws[i];
    int ex = wbase + inc - v;
    if (t < nbuck) { boffs[t] = ex; bhead[t] = ex; }
    if (t == nbuck - 1) boffs[nbuck] = ex + v;
}

// tile = 4096 edges per WG, 1024 threads (4 edges/thread): LDS counting-sort by
// coarse bucket, then write the reordered tile in per-bucket runs (~21 edges).
__global__ __launch_bounds__(1024) void scatterA_kernel(const int* __restrict__ src,
                                                        const int* __restrict__ dst,
                                                        const int* __restrict__ et,
                                                        int* __restrict__ bhead,
                                                        int* __restrict__ sortedA, int E, int nbuck) {
    __shared__ int skey[TILE];
    __shared__ unsigned char sbkt[TILE];
    __shared__ int cnt[256];
    __shared__ int lpos[256];
    __shared__ int gdelta[256];
    __shared__ int ws[4];
    const int t = threadIdx.x;
    const int e0 = blockIdx.x * TILE;
    int dreg[4];

    if (t < 256) cnt[t] = 0;
    __syncthreads();
    #pragma unroll
    for (int j = 0; j < 4; ++j) {
        int e = e0 + j * 1024 + t;
        int d = -1;
        if (e < E) { d = dst[e]; atomicAdd(&cnt[d >> BSH], 1); }
        dreg[j] = d;
    }
    __syncthreads();
    int c = 0, inc = 0;
    const int lane = t & 63, w = t >> 6;
    if (t < 256) {
        c = cnt[t];
        inc = c;
        #pragma unroll
        for (int off = 1; off < 64; off <<= 1) {
            int n = __shfl_up(inc, off, 64);
            if (lane >= off) inc += n;
        }
        if (lane == 63) ws[w] = inc;
    }
    __syncthreads();
    if (t < 256) {
        int wbase = 0;
        for (int i = 0; i < w; ++i) wbase += ws[i];
        int ex = wbase + inc - c;
        lpos[t] = ex;
        if (c) gdelta[t] = atomicAdd(&bhead[t], c) - ex;
    }
    __syncthreads();
    #pragma unroll
    for (int j = 0; j < 4; ++j) {
        int e = e0 + j * 1024 + t;
        if (e < E) {
            int d = dreg[j];
            int b = d >> BSH;
            int key = ((d & (BSZ - 1)) << 20) | (et[e] << 17) | src[e];
            int p = atomicAdd(&lpos[b], 1);
            skey[p] = key;
            sbkt[p] = (unsigned char)b;
        }
    }
    __syncthreads();
    int ntile = min(TILE, E - e0);
    for (int i = t; i < ntile; i += 1024)
        sortedA[gdelta[sbkt[i]] + i] = skey[i];
}

// ---------------- sort pass B: per-bucket fine sort by (node,rel) -> offs2[] + sorted[] ----------------
// 512 threads: grid is only 196 WGs, so intra-WG parallelism is the lever.

__global__ __launch_bounds__(512) void passB_kernel(const int* __restrict__ sortedA,
                                                    const int* __restrict__ boffs,
                                                    int* __restrict__ sorted,
                                                    int* __restrict__ offs2,
                                                    int N8, int E, int nbuck) {
    __shared__ int cnt[4096];
    __shared__ int cur[4096];
    __shared__ int ws[8];
    const int b = blockIdx.x;
    const int t = threadIdx.x;          // 0..511
    const int gb0 = boffs[b], gb1 = boffs[b + 1];
    #pragma unroll
    for (int i = 0; i < 8; ++i) cnt[i * 512 + t] = 0;
    __syncthreads();
    for (int e = gb0 + t; e < gb1; e += 512) {
        int k = sortedA[e];
        atomicAdd(&cnt[(k >> 17) & 4095], 1);   // (dst_low << 3) | etype
    }
    __syncthreads();
    const int base = t * 8;             // 512 threads x 8 counters
    int s = 0;
    #pragma unroll
    for (int i = 0; i < 8; ++i) s += cnt[base + i];
    int lane = t & 63, w = t >> 6;      // w: 0..7
    int inc = s;
    #pragma unroll
    for (int off = 1; off < 64; off <<= 1) {
        int n = __shfl_up(inc, off, 64);
        if (lane >= off) inc += n;
    }
    if (lane == 63) ws[w] = inc;
    __syncthreads();
    int wbase = 0;
    for (int i = 0; i < w; ++i) wbase += ws[i];
    int run = gb0 + wbase + inc - s;
    int g0 = (b << 12) + base;
    #pragma unroll
    for (int i = 0; i < 8; ++i) {
        int cv = cnt[base + i];
        cur[base + i] = run;
        if (g0 + i <= N8) offs2[g0 + i] = run;
        run += cv;
    }
    __syncthreads();
    // final scatter: all writes land inside this bucket's ~32KB window (L2-hot) -> no amplification
    for (int e = gb0 + t; e < gb1; e += 512) {
        int k = sortedA[e];
        int p = atomicAdd(&cur[(k >> 17) & 4095], 1);
        sorted[p] = k;
    }
}

// ---------------- combined cast: Bt[o][k] bf16 (both layers) + hb0 bf16 ----------------

__global__ void cast_kernel(const float* __restrict__ W1, const float* __restrict__ lw1,
                            const float* __restrict__ W2, const float* __restrict__ lw2,
                            const float* __restrict__ feats,
                            unsigned short* __restrict__ Bt1, unsigned short* __restrict__ Bt2,
                            unsigned short* __restrict__ hb0, int n4) {
    const int per = KTOT * D;          // 147456
    int idx = blockIdx.x * blockDim.x + threadIdx.x;
    if (idx < 2 * per) {
        int layer = idx / per;
        int rem = idx - layer * per;
        int k = rem >> 7;
        int o = rem & 127;             // coalesced read dim
        const float* W  = layer ? W2 : W1;
        const float* lw = layer ? lw2 : lw1;
        float val = (k < 1024) ? W[k * D + o] : lw[(k - 1024) * D + o];
        unsigned short* Bt = layer ? Bt2 : Bt1;
        Bt[o * KTOT + k] = f2bf(val);
    } else {
        int i = idx - 2 * per;
        if (i < n4) {
            float4 v = *(const float4*)(feats + (size_t)i * 4);
            us4 o; o.x = f2bf(v.x); o.y = f2bf(v.y); o.z = f2bf(v.z); o.w = f2bf(v.w);
            *(us4*)(hb0 + (size_t)i * 4) = o;
        }
    }
}

// ---------------- aggregation: one (node,rel) SEGMENT per 16-lane unit ----------------
// ACC store NONTEMPORAL (write-once stream): keeps the 200MB write stream from
// evicting the L3-resident hb gather table. Loads stay normal.

__global__ __launch_bounds__(256) void aggregate_kernel(const unsigned short* __restrict__ hb,
                                                        const int* __restrict__ offs2,
                                                        const int* __restrict__ sorted,
                                                        unsigned short* __restrict__ A,
                                                        int v0, int vend) {
    const int t = threadIdx.x;
    const int c = (t & 15) * 8;            // 8 bf16 cols per lane
    const int gu = blockIdx.x * 16 + (t >> 4);
    const int v = v0 + (gu >> 3);
    const int r = gu & 7;
    if (v >= vend) return;

    const int e0 = offs2[v * 8 + r];
    const int e1 = offs2[v * 8 + r + 1];

    float a0[8], a1[8];
    #pragma unroll
    for (int j = 0; j < 8; ++j) { a0[j] = 0.f; a1[j] = 0.f; }

    int e = e0;
    for (; e + 1 < e1; e += 2) {
        int p0 = sorted[e], p1 = sorted[e + 1];
        us8 h0 = *(const us8*)(hb + (size_t)(p0 & 131071) * D + c);
        us8 h1 = *(const us8*)(hb + (size_t)(p1 & 131071) * D + c);
        #pragma unroll
        for (int j = 0; j < 8; ++j) { a0[j] += bf2f(h0[j]); a1[j] += bf2f(h1[j]); }
    }
    if (e < e1) {
        int p0 = sorted[e];
        us8 h0 = *(const us8*)(hb + (size_t)(p0 & 131071) * D + c);
        #pragma unroll
        for (int j = 0; j < 8; ++j) a0[j] += bf2f(h0[j]);
    }

    us8 o;
    #pragma unroll
    for (int j = 0; j < 8; ++j) o[j] = f2bf(a0[j] + a1[j]);
    ntstore16(A + (size_t)(v - v0) * KACC + r * 128 + c, o);
}

// ---------------- GEMM: out[0:N][128] = [ACC | hb_self] @ Bt^T + bias (+ReLU) ----------------
// BM=64, full grid (1563 WGs = 6 WG/CU), register prefetch distance 1.

__global__ __launch_bounds__(256) void gemm_kernel(const unsigned short* __restrict__ A,
                                                   const unsigned short* __restrict__ hbA,
                                                   const unsigned short* __restrict__ Bt,
                                                   const float* __restrict__ bias,
                                                   float* __restrict__ outf,
                                                   unsigned short* __restrict__ outb,
                                                   int v0, int vend, int relu_bf) {
    __shared__ unsigned short Alds[64 * 32];
    __shared__ unsigned short Blds[128 * 32];
    const int t = threadIdx.x;
    const int lane = t & 63;
    const int w = t >> 6;
    const int quad = lane >> 4;
    const int c16 = lane & 15;
    const int blockRow0 = v0 + blockIdx.x * 64;

    const int srow = t >> 2;           // 0..63
    const int schunk = t & 3;

    f32x4 acc[8];
    #pragma unroll
    for (int j = 0; j < 8; ++j) acc[j] = f32x4{0.f, 0.f, 0.f, 0.f};

    const int aRow = blockRow0 + srow;
    const bool aval = aRow < vend;
    const us8 zz = {0, 0, 0, 0, 0, 0, 0, 0};
    const unsigned short* Arow = A + (size_t)(aRow - v0) * KACC + schunk * 8;
    const unsigned short* Hrow = hbA + (size_t)aRow * D + schunk * 8;
    const unsigned short* Brow0 = Bt + (size_t)srow * KTOT + schunk * 8;
    const unsigned short* Brow1 = Bt + (size_t)(srow + 64) * KTOT + schunk * 8;

    // prologue: prefetch K-step 0
    us8 av = zz;
    if (aval) av = *(const us8*)(Arow);
    us8 bv0 = *(const us8*)(Brow0);
    us8 bv1 = *(const us8*)(Brow1);

    for (int k0 = 0; k0 < KTOT; k0 += BK) {
        us8 na = zz, nb0 = zz, nb1 = zz;
        const int kn = k0 + BK;
        if (kn < KTOT) {
            if (aval) {
                if (kn < KACC) na = *(const us8*)(Arow + kn);
                else           na = *(const us8*)(Hrow + (kn - KACC));
            }
            nb0 = *(const us8*)(Brow0 + kn);
            nb1 = *(const us8*)(Brow1 + kn);
        }
        __syncthreads();
        *(us8*)(Alds + lds_off(srow, schunk)) = av;
        *(us8*)(Blds + lds_off(srow,      schunk)) = bv0;
        *(us8*)(Blds + lds_off(srow + 64, schunk)) = bv1;
        __syncthreads();

        bf16x8 af = *(const bf16x8*)(Alds + lds_off(w * 16 + c16, quad));
        #pragma unroll
        for (int ct = 0; ct < 8; ++ct) {
            bf16x8 bfr = *(const bf16x8*)(Blds + lds_off(ct * 16 + c16, quad));
            acc[ct] = __builtin_amdgcn_mfma_f32_16x16x32_bf16(af, bfr, acc[ct], 0, 0, 0);
        }
        av = na; bv0 = nb0; bv1 = nb1;
    }

    // epilogue: C[row=quad*4+i][col=c16] per 16x16 tile
    int row = blockRow0 + w * 16 + quad * 4;
    #pragma unroll
    for (int ct = 0; ct < 8; ++ct) {
        int col = ct * 16 + c16;
        float bcol = bias[col];
        #pragma unroll
        for (int i = 0; i < 4; ++i) {
            int r = row + i;
            if (r < vend) {
                float vv = acc[ct][i] + bcol;
                if (relu_bf) {
                    vv = fmaxf(vv, 0.f);
                    outb[(size_t)r * D + col] = f2bf(vv);
                } else {
                    outf[(size_t)r * D + col] = vv;
                }
            }
        }
    }
}

// ---------------- launch ----------------

extern "C" void kernel_launch(void* const* d_in, const int* in_sizes, int n_in,
                              void* d_out, int out_size, void* d_ws, size_t ws_size,
                              hipStream_t stream) {
    const float* feats = (const float*)d_in[0];
    const float* W1    = (const float*)d_in[1];
    const float* lw1   = (const float*)d_in[2];
    const float* b1    = (const float*)d_in[3];
    const float* W2    = (const float*)d_in[4];
    const float* lw2   = (const float*)d_in[5];
    const float* b2    = (const float*)d_in[6];
    const int*   src   = (const int*)d_in[7];
    const int*   dst   = (const int*)d_in[8];
    const int*   etype = (const int*)d_in[9];
    const int N = in_sizes[0] / D;
    const int E = in_sizes[7];
    float* out = (float*)d_out;

    const int nbuck = (N + BSZ - 1) >> BSH;

    size_t woff = 0;
    auto take = [&](size_t bytes) -> void* {
        void* p = (char*)d_ws + woff;
        woff += (bytes + 255) & ~(size_t)255;
        return p;
    };
    // Full-size ACC first; sort scratch (dead before aggregate) aliases its head.
    unsigned short* ACC = (unsigned short*)take((size_t)N * KACC * 2);   // 204.8 MB
    int* sortedA        = (int*)ACC;                                     // E*4 = 6.4 MB
    int* bcnt           = (int*)((char*)ACC + (((size_t)E * 4 + 255) & ~(size_t)255));
    int* boffs          = bcnt + 1024;
    int* bhead          = boffs + 1032;
    // Persistent buffers (live across both layers):
    int* offs2          = (int*)take((size_t)(N * 8 + 1) * 4);
    int* sorted         = (int*)take((size_t)E * 4);
    unsigned short* Bt1 = (unsigned short*)take((size_t)KTOT * D * 2);
    unsigned short* Bt2 = (unsigned short*)take((size_t)KTOT * D * 2);
    unsigned short* hb0 = (unsigned short*)take((size_t)N * D * 2);
    unsigned short* hb1 = (unsigned short*)take((size_t)N * D * 2);

    (void)hipMemsetAsync(bcnt, 0, (size_t)nbuck * 4, stream);

    histA_kernel<<<1024, 256, 0, stream>>>(dst, bcnt, E, nbuck);
    scanA_kernel<<<1, 1024, 0, stream>>>(bcnt, boffs, bhead, nbuck);
    scatterA_kernel<<<(E + TILE - 1) / TILE, 1024, 0, stream>>>(src, dst, etype, bhead, sortedA, E, nbuck);
    passB_kernel<<<nbuck, 512, 0, stream>>>(sortedA, boffs, sorted, offs2, N * 8, E, nbuck);

    int n4 = N * D / 4;
    int cb = (2 * KTOT * D + n4 + 255) / 256;
    cast_kernel<<<cb, 256, 0, stream>>>(W1, lw1, W2, lw2, feats, Bt1, Bt2, hb0, n4);

    int ab = (N * 8 + 15) / 16;        // one (node,rel) segment per 16-lane unit
    int gb = (N + 63) / 64;
    for (int layer = 0; layer < 2; ++layer) {
        const unsigned short* hin = layer ? hb1 : hb0;
        const unsigned short* Bt  = layer ? Bt2 : Bt1;
        const float* bias         = layer ? b2  : b1;
        aggregate_kernel<<<ab, 256, 0, stream>>>(hin, offs2, sorted, ACC, 0, N);
        gemm_kernel<<<gb, 256, 0, stream>>>(ACC, hin, Bt, bias, out, hb1, 0, N, 1 - layer);
    }
}

// Round 17
// 505.741 us; speedup vs baseline: 1.0834x; 1.0834x over previous
//
#include <hip/hip_runtime.h>
#include <hip/hip_bf16.h>

// R-GCN 2-layer forward, round-19: revert round-18's nt-store (refuted BOTH
// ways: nt-load r11b hurt gemm, nt-store r18 hurt gemm via lost L2/L3 hits on
// ACC — the ACC stream must stay cached). Base = round-17 (506us).
// One change: gemm LDS DOUBLE-BUFFER -> 1 barrier per K-step (was 2).
// Per iter: issue k+1 loads -> barrier -> MFMA from buf[cur] (covers vmcnt)
// -> ds_write k+1 into buf[cur^1] -> flip. LDS 24KB keeps 6 WG/CU.

#define D 128
#define KTOT 1152
#define KACC 1024
#define BK 32
#define BSH 9            // log2(coarse bucket size in nodes)
#define BSZ 512          // nodes per coarse bucket
#define TILE 4096        // edges per scatterA WG

typedef __attribute__((ext_vector_type(8))) __bf16 bf16x8;
typedef __attribute__((ext_vector_type(8))) unsigned short us8;
typedef __attribute__((ext_vector_type(4))) unsigned short us4;
typedef __attribute__((ext_vector_type(4))) float f32x4;

__device__ __forceinline__ unsigned short f2bf(float f) {
    union { float f; unsigned u; } v; v.f = f;
    unsigned r = v.u + 0x7FFF + ((v.u >> 16) & 1);   // RNE
    return (unsigned short)(r >> 16);
}
__device__ __forceinline__ float bf2f(unsigned short u) {
    return __uint_as_float((unsigned)u << 16);
}

__device__ __forceinline__ int lds_off(int row, int c) {
    return row * 32 + ((c ^ ((row >> 1) & 3)) << 3);
}

// ---------------- sort pass A: coarse-bucket histogram / scan / tile-sorted scatter ----------------

__global__ __launch_bounds__(256) void histA_kernel(const int* __restrict__ dst,
                                                    int* __restrict__ bcnt, int E, int nbuck) {
    __shared__ int c[1024];
    int t = threadIdx.x;
    for (int i = t; i < nbuck; i += 256) c[i] = 0;
    __syncthreads();
    int stride = gridDim.x * 256;
    for (int e = blockIdx.x * 256 + t; e < E; e += stride)
        atomicAdd(&c[dst[e] >> BSH], 1);
    __syncthreads();
    for (int i = t; i < nbuck; i += 256)
        if (c[i]) atomicAdd(&bcnt[i], c[i]);
}

__global__ __launch_bounds__(1024) void scanA_kernel(const int* __restrict__ bcnt,
                                                     int* __restrict__ boffs,
                                                     int* __restrict__ bhead, int nbuck) {
    int t = threadIdx.x;
    int v = (t < nbuck) ? bcnt[t] : 0;
    int lane = t & 63, w = t >> 6;
    int inc = v;
    #pragma unroll
    for (int off = 1; off < 64; off <<= 1) {
        int n = __shfl_up(inc, off, 64);
        if (lane >= off) inc += n;
    }
    __shared__ int ws[16];
    if (lane == 63) ws[w] = inc;
    __syncthreads();
    int wbase = 0;
    for (int i = 0; i < w; ++i) wbase += ws[i];
    int ex = wbase + inc - v;
    if (t < nbuck) { boffs[t] = ex; bhead[t] = ex; }
    if (t == nbuck - 1) boffs[nbuck] = ex + v;
}

// tile = 4096 edges per WG, 1024 threads (4 edges/thread): LDS counting-sort by
// coarse bucket, then write the reordered tile in per-bucket runs (~21 edges).
__global__ __launch_bounds__(1024) void scatterA_kernel(const int* __restrict__ src,
                                                        const int* __restrict__ dst,
                                                        const int* __restrict__ et,
                                                        int* __restrict__ bhead,
                                                        int* __restrict__ sortedA, int E, int nbuck) {
    __shared__ int skey[TILE];
    __shared__ unsigned char sbkt[TILE];
    __shared__ int cnt[256];
    __shared__ int lpos[256];
    __shared__ int gdelta[256];
    __shared__ int ws[4];
    const int t = threadIdx.x;
    const int e0 = blockIdx.x * TILE;
    int dreg[4];

    if (t < 256) cnt[t] = 0;
    __syncthreads();
    #pragma unroll
    for (int j = 0; j < 4; ++j) {
        int e = e0 + j * 1024 + t;
        int d = -1;
        if (e < E) { d = dst[e]; atomicAdd(&cnt[d >> BSH], 1); }
        dreg[j] = d;
    }
    __syncthreads();
    int c = 0, inc = 0;
    const int lane = t & 63, w = t >> 6;
    if (t < 256) {
        c = cnt[t];
        inc = c;
        #pragma unroll
        for (int off = 1; off < 64; off <<= 1) {
            int n = __shfl_up(inc, off, 64);
            if (lane >= off) inc += n;
        }
        if (lane == 63) ws[w] = inc;
    }
    __syncthreads();
    if (t < 256) {
        int wbase = 0;
        for (int i = 0; i < w; ++i) wbase += ws[i];
        int ex = wbase + inc - c;
        lpos[t] = ex;
        if (c) gdelta[t] = atomicAdd(&bhead[t], c) - ex;
    }
    __syncthreads();
    #pragma unroll
    for (int j = 0; j < 4; ++j) {
        int e = e0 + j * 1024 + t;
        if (e < E) {
            int d = dreg[j];
            int b = d >> BSH;
            int key = ((d & (BSZ - 1)) << 20) | (et[e] << 17) | src[e];
            int p = atomicAdd(&lpos[b], 1);
            skey[p] = key;
            sbkt[p] = (unsigned char)b;
        }
    }
    __syncthreads();
    int ntile = min(TILE, E - e0);
    for (int i = t; i < ntile; i += 1024)
        sortedA[gdelta[sbkt[i]] + i] = skey[i];
}

// ---------------- sort pass B: per-bucket fine sort by (node,rel) -> offs2[] + sorted[] ----------------
// 512 threads: grid is only 196 WGs, so intra-WG parallelism is the lever.

__global__ __launch_bounds__(512) void passB_kernel(const int* __restrict__ sortedA,
                                                    const int* __restrict__ boffs,
                                                    int* __restrict__ sorted,
                                                    int* __restrict__ offs2,
                                                    int N8, int E, int nbuck) {
    __shared__ int cnt[4096];
    __shared__ int cur[4096];
    __shared__ int ws[8];
    const int b = blockIdx.x;
    const int t = threadIdx.x;          // 0..511
    const int gb0 = boffs[b], gb1 = boffs[b + 1];
    #pragma unroll
    for (int i = 0; i < 8; ++i) cnt[i * 512 + t] = 0;
    __syncthreads();
    for (int e = gb0 + t; e < gb1; e += 512) {
        int k = sortedA[e];
        atomicAdd(&cnt[(k >> 17) & 4095], 1);   // (dst_low << 3) | etype
    }
    __syncthreads();
    const int base = t * 8;             // 512 threads x 8 counters
    int s = 0;
    #pragma unroll
    for (int i = 0; i < 8; ++i) s += cnt[base + i];
    int lane = t & 63, w = t >> 6;      // w: 0..7
    int inc = s;
    #pragma unroll
    for (int off = 1; off < 64; off <<= 1) {
        int n = __shfl_up(inc, off, 64);
        if (lane >= off) inc += n;
    }
    if (lane == 63) ws[w] = inc;
    __syncthreads();
    int wbase = 0;
    for (int i = 0; i < w; ++i) wbase += ws[i];
    int run = gb0 + wbase + inc - s;
    int g0 = (b << 12) + base;
    #pragma unroll
    for (int i = 0; i < 8; ++i) {
        int cv = cnt[base + i];
        cur[base + i] = run;
        if (g0 + i <= N8) offs2[g0 + i] = run;
        run += cv;
    }
    __syncthreads();
    // final scatter: all writes land inside this bucket's ~32KB window (L2-hot) -> no amplification
    for (int e = gb0 + t; e < gb1; e += 512) {
        int k = sortedA[e];
        int p = atomicAdd(&cur[(k >> 17) & 4095], 1);
        sorted[p] = k;
    }
}

// ---------------- combined cast: Bt[o][k] bf16 (both layers) + hb0 bf16 ----------------

__global__ void cast_kernel(const float* __restrict__ W1, const float* __restrict__ lw1,
                            const float* __restrict__ W2, const float* __restrict__ lw2,
                            const float* __restrict__ feats,
                            unsigned short* __restrict__ Bt1, unsigned short* __restrict__ Bt2,
                            unsigned short* __restrict__ hb0, int n4) {
    const int per = KTOT * D;          // 147456
    int idx = blockIdx.x * blockDim.x + threadIdx.x;
    if (idx < 2 * per) {
        int layer = idx / per;
        int rem = idx - layer * per;
        int k = rem >> 7;
        int o = rem & 127;             // coalesced read dim
        const float* W  = layer ? W2 : W1;
        const float* lw = layer ? lw2 : lw1;
        float val = (k < 1024) ? W[k * D + o] : lw[(k - 1024) * D + o];
        unsigned short* Bt = layer ? Bt2 : Bt1;
        Bt[o * KTOT + k] = f2bf(val);
    } else {
        int i = idx - 2 * per;
        if (i < n4) {
            float4 v = *(const float4*)(feats + (size_t)i * 4);
            us4 o; o.x = f2bf(v.x); o.y = f2bf(v.y); o.z = f2bf(v.z); o.w = f2bf(v.w);
            *(us4*)(hb0 + (size_t)i * 4) = o;
        }
    }
}

// ---------------- aggregation: one (node,rel) SEGMENT per 16-lane unit ----------------

__global__ __launch_bounds__(256) void aggregate_kernel(const unsigned short* __restrict__ hb,
                                                        const int* __restrict__ offs2,
                                                        const int* __restrict__ sorted,
                                                        unsigned short* __restrict__ A,
                                                        int v0, int vend) {
    const int t = threadIdx.x;
    const int c = (t & 15) * 8;            // 8 bf16 cols per lane
    const int gu = blockIdx.x * 16 + (t >> 4);
    const int v = v0 + (gu >> 3);
    const int r = gu & 7;
    if (v >= vend) return;

    const int e0 = offs2[v * 8 + r];
    const int e1 = offs2[v * 8 + r + 1];

    float a0[8], a1[8];
    #pragma unroll
    for (int j = 0; j < 8; ++j) { a0[j] = 0.f; a1[j] = 0.f; }

    int e = e0;
    for (; e + 1 < e1; e += 2) {
        int p0 = sorted[e], p1 = sorted[e + 1];
        us8 h0 = *(const us8*)(hb + (size_t)(p0 & 131071) * D + c);
        us8 h1 = *(const us8*)(hb + (size_t)(p1 & 131071) * D + c);
        #pragma unroll
        for (int j = 0; j < 8; ++j) { a0[j] += bf2f(h0[j]); a1[j] += bf2f(h1[j]); }
    }
    if (e < e1) {
        int p0 = sorted[e];
        us8 h0 = *(const us8*)(hb + (size_t)(p0 & 131071) * D + c);
        #pragma unroll
        for (int j = 0; j < 8; ++j) a0[j] += bf2f(h0[j]);
    }

    us8 o;
    #pragma unroll
    for (int j = 0; j < 8; ++j) o[j] = f2bf(a0[j] + a1[j]);
    *(us8*)(A + (size_t)(v - v0) * KACC + r * 128 + c) = o;
}

// ---------------- GEMM: out[0:N][128] = [ACC | hb_self] @ Bt^T + bias (+ReLU) ----------------
// BM=64, full grid (1563 WGs = 6 WG/CU), register prefetch distance 1,
// LDS DOUBLE-BUFFER: 1 barrier per K-step. 24KB LDS keeps 6 WG/CU.

__global__ __launch_bounds__(256) void gemm_kernel(const unsigned short* __restrict__ A,
                                                   const unsigned short* __restrict__ hbA,
                                                   const unsigned short* __restrict__ Bt,
                                                   const float* __restrict__ bias,
                                                   float* __restrict__ outf,
                                                   unsigned short* __restrict__ outb,
                                                   int v0, int vend, int relu_bf) {
    __shared__ unsigned short Alds[2][64 * 32];
    __shared__ unsigned short Blds[2][128 * 32];
    const int t = threadIdx.x;
    const int lane = t & 63;
    const int w = t >> 6;
    const int quad = lane >> 4;
    const int c16 = lane & 15;
    const int blockRow0 = v0 + blockIdx.x * 64;

    const int srow = t >> 2;           // 0..63
    const int schunk = t & 3;

    f32x4 acc[8];
    #pragma unroll
    for (int j = 0; j < 8; ++j) acc[j] = f32x4{0.f, 0.f, 0.f, 0.f};

    const int aRow = blockRow0 + srow;
    const bool aval = aRow < vend;
    const us8 zz = {0, 0, 0, 0, 0, 0, 0, 0};
    const unsigned short* Arow = A + (size_t)(aRow - v0) * KACC + schunk * 8;
    const unsigned short* Hrow = hbA + (size_t)aRow * D + schunk * 8;
    const unsigned short* Brow0 = Bt + (size_t)srow * KTOT + schunk * 8;
    const unsigned short* Brow1 = Bt + (size_t)(srow + 64) * KTOT + schunk * 8;

    // prologue: load + stage K-step 0 into buf 0
    us8 av = zz;
    if (aval) av = *(const us8*)(Arow);
    us8 bv0 = *(const us8*)(Brow0);
    us8 bv1 = *(const us8*)(Brow1);
    *(us8*)(&Alds[0][0] + lds_off(srow,      schunk)) = av;
    *(us8*)(&Blds[0][0] + lds_off(srow,      schunk)) = bv0;
    *(us8*)(&Blds[0][0] + lds_off(srow + 64, schunk)) = bv1;

    int cur = 0;
    for (int k0 = 0; k0 < KTOT; k0 += BK) {
        const int kn = k0 + BK;
        us8 na = zz, nb0 = zz, nb1 = zz;
        if (kn < KTOT) {
            if (aval) {
                if (kn < KACC) na = *(const us8*)(Arow + kn);
                else           na = *(const us8*)(Hrow + (kn - KACC));
            }
            nb0 = *(const us8*)(Brow0 + kn);
            nb1 = *(const us8*)(Brow1 + kn);
        }
        __syncthreads();                 // buf[cur] writes visible to all waves

        bf16x8 af = *(const bf16x8*)(&Alds[cur][0] + lds_off(w * 16 + c16, quad));
        #pragma unroll
        for (int ct = 0; ct < 8; ++ct) {
            bf16x8 bfr = *(const bf16x8*)(&Blds[cur][0] + lds_off(ct * 16 + c16, quad));
            acc[ct] = __builtin_amdgcn_mfma_f32_16x16x32_bf16(af, bfr, acc[ct], 0, 0, 0);
        }

        if (kn < KTOT) {                 // stage k+1 into the other buffer
            *(us8*)(&Alds[cur ^ 1][0] + lds_off(srow,      schunk)) = na;
            *(us8*)(&Blds[cur ^ 1][0] + lds_off(srow,      schunk)) = nb0;
            *(us8*)(&Blds[cur ^ 1][0] + lds_off(srow + 64, schunk)) = nb1;
        }
        cur ^= 1;
    }

    // epilogue: C[row=quad*4+i][col=c16] per 16x16 tile
    int row = blockRow0 + w * 16 + quad * 4;
    #pragma unroll
    for (int ct = 0; ct < 8; ++ct) {
        int col = ct * 16 + c16;
        float bcol = bias[col];
        #pragma unroll
        for (int i = 0; i < 4; ++i) {
            int r = row + i;
            if (r < vend) {
                float vv = acc[ct][i] + bcol;
                if (relu_bf) {
                    vv = fmaxf(vv, 0.f);
                    outb[(size_t)r * D + col] = f2bf(vv);
                } else {
                    outf[(size_t)r * D + col] = vv;
                }
            }
        }
    }
}

// ---------------- launch ----------------

extern "C" void kernel_launch(void* const* d_in, const int* in_sizes, int n_in,
                              void* d_out, int out_size, void* d_ws, size_t ws_size,
                              hipStream_t stream) {
    const float* feats = (const float*)d_in[0];
    const float* W1    = (const float*)d_in[1];
    const float* lw1   = (const float*)d_in[2];
    const float* b1    = (const float*)d_in[3];
    const float* W2    = (const float*)d_in[4];
    const float* lw2   = (const float*)d_in[5];
    const float* b2    = (const float*)d_in[6];
    const int*   src   = (const int*)d_in[7];
    const int*   dst   = (const int*)d_in[8];
    const int*   etype = (const int*)d_in[9];
    const int N = in_sizes[0] / D;
    const int E = in_sizes[7];
    float* out = (float*)d_out;

    const int nbuck = (N + BSZ - 1) >> BSH;

    size_t woff = 0;
    auto take = [&](size_t bytes) -> void* {
        void* p = (char*)d_ws + woff;
        woff += (bytes + 255) & ~(size_t)255;
        return p;
    };
    // Full-size ACC first; sort scratch (dead before aggregate) aliases its head.
    unsigned short* ACC = (unsigned short*)take((size_t)N * KACC * 2);   // 204.8 MB
    int* sortedA        = (int*)ACC;                                     // E*4 = 6.4 MB
    int* bcnt           = (int*)((char*)ACC + (((size_t)E * 4 + 255) & ~(size_t)255));
    int* boffs          = bcnt + 1024;
    int* bhead          = boffs + 1032;
    // Persistent buffers (live across both layers):
    int* offs2          = (int*)take((size_t)(N * 8 + 1) * 4);
    int* sorted         = (int*)take((size_t)E * 4);
    unsigned short* Bt1 = (unsigned short*)take((size_t)KTOT * D * 2);
    unsigned short* Bt2 = (unsigned short*)take((size_t)KTOT * D * 2);
    unsigned short* hb0 = (unsigned short*)take((size_t)N * D * 2);
    unsigned short* hb1 = (unsigned short*)take((size_t)N * D * 2);

    (void)hipMemsetAsync(bcnt, 0, (size_t)nbuck * 4, stream);

    histA_kernel<<<1024, 256, 0, stream>>>(dst, bcnt, E, nbuck);
    scanA_kernel<<<1, 1024, 0, stream>>>(bcnt, boffs, bhead, nbuck);
    scatterA_kernel<<<(E + TILE - 1) / TILE, 1024, 0, stream>>>(src, dst, etype, bhead, sortedA, E, nbuck);
    passB_kernel<<<nbuck, 512, 0, stream>>>(sortedA, boffs, sorted, offs2, N * 8, E, nbuck);

    int n4 = N * D / 4;
    int cb = (2 * KTOT * D + n4 + 255) / 256;
    cast_kernel<<<cb, 256, 0, stream>>>(W1, lw1, W2, lw2, feats, Bt1, Bt2, hb0, n4);

    int ab = (N * 8 + 15) / 16;        // one (node,rel) segment per 16-lane unit
    int gb = (N + 63) / 64;
    for (int layer = 0; layer < 2; ++layer) {
        const unsigned short* hin = layer ? hb1 : hb0;
        const unsigned short* Bt  = layer ? Bt2 : Bt1;
        const float* bias         = layer ? b2  : b1;
        aggregate_kernel<<<ab, 256, 0, stream>>>(hin, offs2, sorted, ACC, 0, N);
        gemm_kernel<<<gb, 256, 0, stream>>>(ACC, hin, Bt, bias, out, hb1, 0, N, 1 - layer);
    }
}